// Round 7
// baseline (191.438 us; speedup 1.0000x reference)
//
#include <hip/hip_runtime.h>
#include <math.h>

#define BB      2
#define C_CT    128
#define CB      32
#define NN      180
#define VV      13824      // 24*24*24
#define NPG     45         // NN/4
#define SCALE   0.17677669529663687f

typedef float vfloat4 __attribute__((ext_vector_type(4)));

// ============================ K0: q projection ============================
// q[b][c][v] written into the fused-output region of `out` (dead until K2
// overwrites it; K1 consumes it in between).
__global__ __launch_bounds__(256, 2)
void qproj_kernel(const float* __restrict__ ct, const float* __restrict__ qw,
                  const float* __restrict__ qb, float* __restrict__ qout)
{
    __shared__ float qw_t[C_CT * 33];                 // [c][o], +1 pad
    __shared__ __align__(16) float ct_s[C_CT * 64];   // [c][v]
    __shared__ float q_s[64 * 33];                    // [v][o], +1 pad
    __shared__ float qb_s[CB];
    const int t  = threadIdx.x;
    const int b  = blockIdx.x / 216;
    const int v0 = (blockIdx.x % 216) * 64;

    for (int i = t; i < CB * C_CT; i += 256) {
        const int o = i >> 7, c = i & 127;
        qw_t[c * 33 + o] = qw[i];
    }
    {
        const float* ctbase = ct + (size_t)b * C_CT * VV + v0;
        for (int i = t; i < C_CT * 16; i += 256) {   // 2048 float4
            const int c = i >> 4, k = i & 15;
            *reinterpret_cast<vfloat4*>(&ct_s[c * 64 + k * 4]) =
                *reinterpret_cast<const vfloat4*>(ctbase + (size_t)c * VV + k * 4);
        }
    }
    if (t < CB) qb_s[t] = qb[t];
    __syncthreads();

    const int o = t & 31, va = t >> 5;   // thread: channel o, voxels va+8k
    float a[8];
    #pragma unroll
    for (int k = 0; k < 8; ++k) a[k] = qb_s[o];
    for (int kc = 0; kc < C_CT; ++kc) {
        const float wk = qw_t[kc * 33 + o];          // conflict-free
        const float* cr = &ct_s[kc * 64];
        #pragma unroll
        for (int k = 0; k < 8; ++k) a[k] = fmaf(wk, cr[va + 8 * k], a[k]);
    }
    #pragma unroll
    for (int k = 0; k < 8; ++k) q_s[(va + 8 * k) * 33 + o] = a[k];
    __syncthreads();

    for (int i = t; i < CB * 64; i += 256) {         // transpose-write [c][v]
        const int c = i >> 6, v = i & 63;
        qout[((size_t)b * CB + c) * VV + v0 + v] = q_s[v * 33 + c];
    }
}

// ============================ K1: beam stream =============================
// One wave per (b, 64-voxel tile, n-quarter). 1728 units -> 6.75/CU, 3.7% imb.
// No LDS, no barriers. Depth-3 prefetch. W unnormalized -> attn region of out;
// acc/l partials -> ws.
__global__ __launch_bounds__(64, 2)
void stream_kernel(const float* __restrict__ beam, const float* __restrict__ qarr,
                   float* __restrict__ wout, float* __restrict__ ws_acc,
                   float* __restrict__ ws_l)
{
    const int u  = blockIdx.x;
    const int b  = u / 864;
    const int r  = u % 864;
    const int g  = r & 3;            // n-quarter
    const int v0 = (r >> 2) * 64;
    const int lane = threadIdx.x;
    const int vq = lane & 15;        // voxel quad (voxels vq*4..+3)
    const int cg = lane >> 4;        // channel group (channels cg*8..+7)

    float q[8][4];
    #pragma unroll
    for (int ci = 0; ci < 8; ++ci) {
        vfloat4 qv = *reinterpret_cast<const vfloat4*>(
            qarr + ((size_t)b * CB + cg * 8 + ci) * VV + v0 + vq * 4);
        q[ci][0] = qv.x; q[ci][1] = qv.y; q[ci][2] = qv.z; q[ci][3] = qv.w;
    }

    float acc[8][4];
    #pragma unroll
    for (int ci = 0; ci < 8; ++ci)
        acc[ci][0] = acc[ci][1] = acc[ci][2] = acc[ci][3] = 0.f;
    float l0 = 0.f, l1 = 0.f, l2 = 0.f, l3 = 0.f;

    const float* bpc  = beam + (((size_t)b * NN + g * NPG) * CB + cg * 8) * VV + v0 + vq * 4;
    float*       wrow = wout + ((size_t)b * VV + v0 + vq * 4) * NN + g * NPG;

    vfloat4 kvA[8], kvB[8], kvC[8];
    auto loadK = [&](vfloat4* kv, int i) {
        const float* p = bpc + (size_t)i * (CB * VV);
        #pragma unroll
        for (int ci = 0; ci < 8; ++ci)
            kv[ci] = __builtin_nontemporal_load(
                reinterpret_cast<const vfloat4*>(p + (size_t)ci * VV));
    };
    auto computeK = [&](const vfloat4* kv, int i) {
        float p0 = 0.f, p1 = 0.f, p2 = 0.f, p3 = 0.f;
        #pragma unroll
        for (int ci = 0; ci < 8; ++ci) {
            p0 = fmaf(q[ci][0], kv[ci].x, p0);
            p1 = fmaf(q[ci][1], kv[ci].y, p1);
            p2 = fmaf(q[ci][2], kv[ci].z, p2);
            p3 = fmaf(q[ci][3], kv[ci].w, p3);
        }
        p0 += __shfl_xor(p0, 16); p1 += __shfl_xor(p1, 16);
        p2 += __shfl_xor(p2, 16); p3 += __shfl_xor(p3, 16);
        p0 += __shfl_xor(p0, 32); p1 += __shfl_xor(p1, 32);
        p2 += __shfl_xor(p2, 32); p3 += __shfl_xor(p3, 32);
        const float w0 = __expf(fminf(p0 * SCALE, 60.f));
        const float w1 = __expf(fminf(p1 * SCALE, 60.f));
        const float w2 = __expf(fminf(p2 * SCALE, 60.f));
        const float w3 = __expf(fminf(p3 * SCALE, 60.f));
        if (cg == 0) {   // consecutive n per voxel row: L2 write-combines
            wrow[0 * NN + i] = w0;
            wrow[1 * NN + i] = w1;
            wrow[2 * NN + i] = w2;
            wrow[3 * NN + i] = w3;
        }
        l0 += w0; l1 += w1; l2 += w2; l3 += w3;
        #pragma unroll
        for (int ci = 0; ci < 8; ++ci) {
            acc[ci][0] = fmaf(w0, kv[ci].x, acc[ci][0]);
            acc[ci][1] = fmaf(w1, kv[ci].y, acc[ci][1]);
            acc[ci][2] = fmaf(w2, kv[ci].z, acc[ci][2]);
            acc[ci][3] = fmaf(w3, kv[ci].w, acc[ci][3]);
        }
    };

    loadK(kvA, 0);
    loadK(kvB, 1);
    #pragma unroll 1
    for (int i = 0; i < NPG; i += 3) {        // 45 = 3*15, exact
        loadK(kvC, i + 2);
        computeK(kvA, i);
        if (i + 3 < NPG) loadK(kvA, i + 3);
        computeK(kvB, i + 1);
        if (i + 4 < NPG) loadK(kvB, i + 4);
        computeK(kvC, i + 2);
    }

    #pragma unroll
    for (int ci = 0; ci < 8; ++ci) {
        vfloat4 a; a.x = acc[ci][0]; a.y = acc[ci][1]; a.z = acc[ci][2]; a.w = acc[ci][3];
        *reinterpret_cast<vfloat4*>(
            ws_acc + (((size_t)b * 4 + g) * CB + cg * 8 + ci) * VV + v0 + vq * 4) = a;
    }
    if (cg == 0) {
        vfloat4 lv; lv.x = l0; lv.y = l1; lv.z = l2; lv.w = l3;
        *reinterpret_cast<vfloat4*>(ws_l + ((size_t)b * 4 + g) * VV + v0 + vq * 4) = lv;
    }
}

// ===================== K2: combine + LN + attn normalize ==================
__global__ __launch_bounds__(256, 4)
void combine_kernel(const float* __restrict__ ws_acc, const float* __restrict__ ws_l,
                    const float* __restrict__ gam, const float* __restrict__ bet,
                    float* __restrict__ out)
{
    __shared__ float il_s[32];
    const int t  = threadIdx.x;
    const int b  = blockIdx.x / 432;
    const int v0 = (blockIdx.x % 432) * 32;

    if (t < 32) {
        const int v = v0 + t;
        float lt = 0.f;
        #pragma unroll
        for (int g = 0; g < 4; ++g) lt += ws_l[((size_t)b * 4 + g) * VV + v];
        const float il = 1.f / lt;
        il_s[t] = il;
        float f[CB], mu = 0.f;
        #pragma unroll
        for (int c = 0; c < CB; ++c) {
            float s = 0.f;
            #pragma unroll
            for (int g = 0; g < 4; ++g)
                s += ws_acc[(((size_t)b * 4 + g) * CB + c) * VV + v];   // 128B coalesced
            f[c] = s * il;
            mu += f[c];
        }
        mu *= (1.f / CB);
        float var = 0.f;
        #pragma unroll
        for (int c = 0; c < CB; ++c) { const float d = f[c] - mu; var = fmaf(d, d, var); }
        const float rs = rsqrtf(var * (1.f / CB) + 1e-5f);
        float* op = out + (size_t)b * CB * VV + v;
        #pragma unroll
        for (int c = 0; c < CB; ++c)
            op[(size_t)c * VV] = (f[c] - mu) * rs * gam[c] + bet[c];
    }
    __syncthreads();

    {   // normalize attn rows in place: 32 voxels x 45 float4
        const int v  = t >> 3;
        const int kk = t & 7;
        const float il = il_s[v];
        float* arow = out + (size_t)BB * CB * VV + ((size_t)b * VV + v0 + v) * NN;
        #pragma unroll
        for (int m = 0; m < 6; ++m) {
            const int q4 = kk + m * 8;
            if (q4 < NN / 4) {
                vfloat4 wv = *reinterpret_cast<const vfloat4*>(arow + q4 * 4);
                wv.x *= il; wv.y *= il; wv.z *= il; wv.w *= il;
                *reinterpret_cast<vfloat4*>(arow + q4 * 4) = wv;
            }
        }
    }
}

// ===================== Fallback: R4 single kernel (ws too small) ==========
__global__ __launch_bounds__(256, 2)
void vmat_attn_fallback(const float* __restrict__ ct, const float* __restrict__ beam,
                        const float* __restrict__ qw, const float* __restrict__ qb,
                        const float* __restrict__ gam, const float* __restrict__ bet,
                        float* __restrict__ out)
{
    __shared__ __align__(16) float Wbuf[NN * 64];
    __shared__ __align__(16) float Pbuf[4][CB][64];
    __shared__ __align__(16) float l_part[4][64];
    __shared__ float l_final[64];
    __shared__ float qb_s[CB], gam_s[CB], bet_s[CB];

    const int t = threadIdx.x, lane = t & 63, g = t >> 6;
    const int vq = lane & 15, cg = lane >> 4;
    const int bid = blockIdx.x, b = bid / 216, v0 = (bid % 216) * 64;

    for (int i = t; i < CB * C_CT; i += 256) Wbuf[i] = qw[i];
    if (t < CB) { qb_s[t] = qb[t]; gam_s[t] = gam[t]; bet_s[t] = bet[t]; }
    __syncthreads();
    {
        const int v = v0 + lane;
        const float* ctp = ct + ((size_t)b * C_CT + g * 32) * VV + v;
        float ctv[32];
        #pragma unroll
        for (int j = 0; j < 32; ++j) ctv[j] = ctp[(size_t)j * VV];
        float qp[CB];
        #pragma unroll
        for (int o = 0; o < CB; ++o) qp[o] = 0.f;
        for (int j = 0; j < 32; ++j) {
            #pragma unroll
            for (int o = 0; o < CB; ++o)
                qp[o] = fmaf(Wbuf[o * C_CT + g * 32 + j], ctv[j], qp[o]);
        }
        #pragma unroll
        for (int o = 0; o < CB; ++o) Pbuf[g][o][lane] = qp[o];
    }
    __syncthreads();
    float q[8][4];
    #pragma unroll
    for (int ci = 0; ci < 8; ++ci) {
        const int o = cg * 8 + ci;
        vfloat4 a0 = *reinterpret_cast<const vfloat4*>(&Pbuf[0][o][vq * 4]);
        vfloat4 a1 = *reinterpret_cast<const vfloat4*>(&Pbuf[1][o][vq * 4]);
        vfloat4 a2 = *reinterpret_cast<const vfloat4*>(&Pbuf[2][o][vq * 4]);
        vfloat4 a3 = *reinterpret_cast<const vfloat4*>(&Pbuf[3][o][vq * 4]);
        q[ci][0] = a0.x + a1.x + a2.x + a3.x + qb_s[o];
        q[ci][1] = a0.y + a1.y + a2.y + a3.y + qb_s[o];
        q[ci][2] = a0.z + a1.z + a2.z + a3.z + qb_s[o];
        q[ci][3] = a0.w + a1.w + a2.w + a3.w + qb_s[o];
    }
    __syncthreads();
    float acc[8][4];
    #pragma unroll
    for (int ci = 0; ci < 8; ++ci)
        acc[ci][0] = acc[ci][1] = acc[ci][2] = acc[ci][3] = 0.f;
    float l0 = 0.f, l1 = 0.f, l2 = 0.f, l3 = 0.f;
    const float* bp0 = beam + (((size_t)b * NN + g * NPG) * CB + cg * 8) * VV + v0 + vq * 4;
    vfloat4 kvA[8], kvB[8];
    auto loadK = [&](vfloat4* kv, int i) {
        const float* bp = bp0 + (size_t)i * CB * VV;
        #pragma unroll
        for (int ci = 0; ci < 8; ++ci)
            kv[ci] = __builtin_nontemporal_load(
                reinterpret_cast<const vfloat4*>(bp + (size_t)ci * VV));
    };
    auto computeK = [&](const vfloat4* kv, int i) {
        float p0 = 0.f, p1 = 0.f, p2 = 0.f, p3 = 0.f;
        #pragma unroll
        for (int ci = 0; ci < 8; ++ci) {
            p0 = fmaf(q[ci][0], kv[ci].x, p0);
            p1 = fmaf(q[ci][1], kv[ci].y, p1);
            p2 = fmaf(q[ci][2], kv[ci].z, p2);
            p3 = fmaf(q[ci][3], kv[ci].w, p3);
        }
        p0 += __shfl_xor(p0, 16); p1 += __shfl_xor(p1, 16);
        p2 += __shfl_xor(p2, 16); p3 += __shfl_xor(p3, 16);
        p0 += __shfl_xor(p0, 32); p1 += __shfl_xor(p1, 32);
        p2 += __shfl_xor(p2, 32); p3 += __shfl_xor(p3, 32);
        float w0 = __expf(fminf(p0 * SCALE, 60.f));
        float w1 = __expf(fminf(p1 * SCALE, 60.f));
        float w2 = __expf(fminf(p2 * SCALE, 60.f));
        float w3 = __expf(fminf(p3 * SCALE, 60.f));
        if (cg == 0) {
            vfloat4 wv; wv.x = w0; wv.y = w1; wv.z = w2; wv.w = w3;
            *reinterpret_cast<vfloat4*>(&Wbuf[(g * NPG + i) * 64 + vq * 4]) = wv;
        }
        l0 += w0; l1 += w1; l2 += w2; l3 += w3;
        #pragma unroll
        for (int ci = 0; ci < 8; ++ci) {
            acc[ci][0] = fmaf(w0, kv[ci].x, acc[ci][0]);
            acc[ci][1] = fmaf(w1, kv[ci].y, acc[ci][1]);
            acc[ci][2] = fmaf(w2, kv[ci].z, acc[ci][2]);
            acc[ci][3] = fmaf(w3, kv[ci].w, acc[ci][3]);
        }
    };
    loadK(kvA, 0);
    #pragma unroll 1
    for (int i = 0; i < NPG - 1; i += 2) {
        loadK(kvB, i + 1);
        computeK(kvA, i);
        if (i + 2 < NPG) loadK(kvA, i + 2);
        computeK(kvB, i + 1);
    }
    computeK(kvA, NPG - 1);
    #pragma unroll
    for (int ci = 0; ci < 8; ++ci) {
        vfloat4 a; a.x = acc[ci][0]; a.y = acc[ci][1]; a.z = acc[ci][2]; a.w = acc[ci][3];
        *reinterpret_cast<vfloat4*>(&Pbuf[g][cg * 8 + ci][vq * 4]) = a;
    }
    if (cg == 0) {
        vfloat4 lv; lv.x = l0; lv.y = l1; lv.z = l2; lv.w = l3;
        *reinterpret_cast<vfloat4*>(&l_part[g][vq * 4]) = lv;
    }
    __syncthreads();
    if (t < 64) {
        float lt = l_part[0][t] + l_part[1][t] + l_part[2][t] + l_part[3][t];
        l_final[t] = lt;
        float inv_l = 1.f / lt;
        float f[CB], mu = 0.f;
        #pragma unroll
        for (int c = 0; c < CB; ++c) {
            f[c] = (Pbuf[0][c][t] + Pbuf[1][c][t] + Pbuf[2][c][t] + Pbuf[3][c][t]) * inv_l;
            mu += f[c];
        }
        mu *= (1.f / CB);
        float var = 0.f;
        #pragma unroll
        for (int c = 0; c < CB; ++c) { float d = f[c] - mu; var = fmaf(d, d, var); }
        float rs = rsqrtf(var * (1.f / CB) + 1e-5f);
        float* op = out + (size_t)b * CB * VV + v0 + t;
        #pragma unroll
        for (int c = 0; c < CB; ++c)
            op[(size_t)c * VV] = (f[c] - mu) * rs * gam_s[c] + bet_s[c];
    }
    __syncthreads();
    {
        const int vv = t & 63, j = t >> 6;
        const float inv_l = 1.f / l_final[vv];
        float* arow = out + (size_t)BB * CB * VV + ((size_t)b * VV + v0 + vv) * NN;
        const int q4b = j * 12, q4e = (j == 3) ? 45 : (j * 12 + 12);
        for (int q4 = q4b; q4 < q4e; ++q4) {
            const int n0 = q4 * 4;
            vfloat4 val;
            val.x = Wbuf[(n0 + 0) * 64 + vv] * inv_l;
            val.y = Wbuf[(n0 + 1) * 64 + vv] * inv_l;
            val.z = Wbuf[(n0 + 2) * 64 + vv] * inv_l;
            val.w = Wbuf[(n0 + 3) * 64 + vv] * inv_l;
            *reinterpret_cast<vfloat4*>(arow + n0) = val;
        }
    }
}

// ================================ launch ==================================
extern "C" void kernel_launch(void* const* d_in, const int* in_sizes, int n_in,
                              void* d_out, int out_size, void* d_ws, size_t ws_size,
                              hipStream_t stream) {
    (void)in_sizes; (void)n_in; (void)out_size;
    const float* ct   = (const float*)d_in[0];
    const float* beam = (const float*)d_in[1];
    const float* qw   = (const float*)d_in[2];
    const float* qb   = (const float*)d_in[3];
    const float* gam  = (const float*)d_in[4];
    const float* bet  = (const float*)d_in[5];
    float* out = (float*)d_out;

    const size_t ACC_FLOATS = (size_t)BB * 4 * CB * VV;   // 3,538,944
    const size_t L_FLOATS   = (size_t)BB * 4 * VV;        //   110,592
    const size_t WS_NEEDED  = (ACC_FLOATS + L_FLOATS) * sizeof(float);

    if (ws_size >= WS_NEEDED) {
        float* ws_acc = (float*)d_ws;
        float* ws_l   = ws_acc + ACC_FLOATS;
        float* qarr   = out;                          // fused region, dead until K2
        float* wout   = out + (size_t)BB * CB * VV;   // attn region
        qproj_kernel  <<<dim3(BB * 216),  256, 0, stream>>>(ct, qw, qb, qarr);
        stream_kernel <<<dim3(BB * 864),   64, 0, stream>>>(beam, qarr, wout, ws_acc, ws_l);
        combine_kernel<<<dim3(BB * 432),  256, 0, stream>>>(ws_acc, ws_l, gam, bet, out);
    } else {
        vmat_attn_fallback<<<dim3(BB * 216), 256, 0, stream>>>(ct, beam, qw, qb, gam, bet, out);
    }
}

// Round 8
// 183.328 us; speedup vs baseline: 1.0442x; 1.0442x over previous
//
#include <hip/hip_runtime.h>
#include <hip/hip_fp16.h>
#include <math.h>

#define BB      2
#define C_CT    128
#define CB      32
#define NN      180
#define VV      13824      // 24*24*24
#define NPG     45         // NN/4
#define SCALE   0.17677669529663687f

typedef float vfloat4 __attribute__((ext_vector_type(4)));

// ============================ K0: q projection ============================
// q[b][c][v] -> fused region of out (dead until K2a overwrites it).
__global__ __launch_bounds__(256, 2)
void qproj_kernel(const float* __restrict__ ct, const float* __restrict__ qw,
                  const float* __restrict__ qb, float* __restrict__ qout)
{
    __shared__ float qw_t[C_CT * 33];                 // [c][o], +1 pad
    __shared__ __align__(16) float ct_s[C_CT * 64];   // [c][v]
    __shared__ float q_s[64 * 33];                    // [v][o], +1 pad
    __shared__ float qb_s[CB];
    const int t  = threadIdx.x;
    const int b  = blockIdx.x / 216;
    const int v0 = (blockIdx.x % 216) * 64;

    for (int i = t; i < CB * C_CT; i += 256) {
        const int o = i >> 7, c = i & 127;
        qw_t[c * 33 + o] = qw[i];
    }
    {
        const float* ctbase = ct + (size_t)b * C_CT * VV + v0;
        for (int i = t; i < C_CT * 16; i += 256) {
            const int c = i >> 4, k = i & 15;
            *reinterpret_cast<vfloat4*>(&ct_s[c * 64 + k * 4]) =
                *reinterpret_cast<const vfloat4*>(ctbase + (size_t)c * VV + k * 4);
        }
    }
    if (t < CB) qb_s[t] = qb[t];
    __syncthreads();

    const int o = t & 31, va = t >> 5;
    float a[8];
    #pragma unroll
    for (int k = 0; k < 8; ++k) a[k] = qb_s[o];
    for (int kc = 0; kc < C_CT; ++kc) {
        const float wk = qw_t[kc * 33 + o];
        const float* cr = &ct_s[kc * 64];
        #pragma unroll
        for (int k = 0; k < 8; ++k) a[k] = fmaf(wk, cr[va + 8 * k], a[k]);
    }
    #pragma unroll
    for (int k = 0; k < 8; ++k) q_s[(va + 8 * k) * 33 + o] = a[k];
    __syncthreads();

    for (int i = t; i < CB * 64; i += 256) {
        const int c = i >> 6, v = i & 63;
        qout[((size_t)b * CB + c) * VV + v0 + v] = q_s[v * 33 + c];
    }
}

// ============================ K1: beam stream =============================
// 1728 one-wave units (b, tile64, n-quarter) -> 6.75/CU, 3.7% imbalance.
// All stores coalesced: W fp16 [n][v] -> ws; acc/l fp32 -> attn region.
__global__ __launch_bounds__(64, 2)
void stream_kernel(const float* __restrict__ beam, const float* __restrict__ qarr,
                   unsigned short* __restrict__ wsW, float* __restrict__ accP,
                   float* __restrict__ lP)
{
    const int u  = blockIdx.x;
    const int b  = u / 864;
    const int r  = u % 864;
    const int g  = r & 3;
    const int v0 = (r >> 2) * 64;
    const int lane = threadIdx.x;
    const int vq = lane & 15;        // voxel quad
    const int cg = lane >> 4;        // channel group (channels cg*8..+7)

    float q[8][4];
    #pragma unroll
    for (int ci = 0; ci < 8; ++ci) {
        vfloat4 qv = *reinterpret_cast<const vfloat4*>(
            qarr + ((size_t)b * CB + cg * 8 + ci) * VV + v0 + vq * 4);
        q[ci][0] = qv.x; q[ci][1] = qv.y; q[ci][2] = qv.z; q[ci][3] = qv.w;
    }

    float acc[8][4];
    #pragma unroll
    for (int ci = 0; ci < 8; ++ci)
        acc[ci][0] = acc[ci][1] = acc[ci][2] = acc[ci][3] = 0.f;
    float l0 = 0.f, l1 = 0.f, l2 = 0.f, l3 = 0.f;

    const float* bpc = beam + (((size_t)b * NN + g * NPG) * CB + cg * 8) * VV + v0 + vq * 4;
    unsigned short* wbase = wsW + ((size_t)(b * NN + g * NPG)) * VV + v0 + vq * 4;

    vfloat4 kvA[8], kvB[8], kvC[8];
    auto loadK = [&](vfloat4* kv, int i) {
        const float* p = bpc + (size_t)i * (CB * VV);
        #pragma unroll
        for (int ci = 0; ci < 8; ++ci)
            kv[ci] = __builtin_nontemporal_load(
                reinterpret_cast<const vfloat4*>(p + (size_t)ci * VV));
    };
    auto computeK = [&](const vfloat4* kv, int i) {
        float p0 = 0.f, p1 = 0.f, p2 = 0.f, p3 = 0.f;
        #pragma unroll
        for (int ci = 0; ci < 8; ++ci) {
            p0 = fmaf(q[ci][0], kv[ci].x, p0);
            p1 = fmaf(q[ci][1], kv[ci].y, p1);
            p2 = fmaf(q[ci][2], kv[ci].z, p2);
            p3 = fmaf(q[ci][3], kv[ci].w, p3);
        }
        p0 += __shfl_xor(p0, 16); p1 += __shfl_xor(p1, 16);
        p2 += __shfl_xor(p2, 16); p3 += __shfl_xor(p3, 16);
        p0 += __shfl_xor(p0, 32); p1 += __shfl_xor(p1, 32);
        p2 += __shfl_xor(p2, 32); p3 += __shfl_xor(p3, 32);
        const float w0 = __expf(fminf(p0 * SCALE, 60.f));
        const float w1 = __expf(fminf(p1 * SCALE, 60.f));
        const float w2 = __expf(fminf(p2 * SCALE, 60.f));
        const float w3 = __expf(fminf(p3 * SCALE, 60.f));
        if (cg == 0) {   // 16 lanes x 8B = 128B contiguous: coalesced
            __half2 h01 = __floats2half2_rn(w0, w1);
            __half2 h23 = __floats2half2_rn(w2, w3);
            uint2 uu;
            uu.x = *reinterpret_cast<unsigned int*>(&h01);
            uu.y = *reinterpret_cast<unsigned int*>(&h23);
            *reinterpret_cast<uint2*>(wbase + (size_t)i * VV) = uu;
        }
        l0 += w0; l1 += w1; l2 += w2; l3 += w3;
        #pragma unroll
        for (int ci = 0; ci < 8; ++ci) {
            acc[ci][0] = fmaf(w0, kv[ci].x, acc[ci][0]);
            acc[ci][1] = fmaf(w1, kv[ci].y, acc[ci][1]);
            acc[ci][2] = fmaf(w2, kv[ci].z, acc[ci][2]);
            acc[ci][3] = fmaf(w3, kv[ci].w, acc[ci][3]);
        }
    };

    loadK(kvA, 0);
    loadK(kvB, 1);
    #pragma unroll 1
    for (int i = 0; i < NPG; i += 3) {        // 45 = 3*15
        loadK(kvC, i + 2);
        computeK(kvA, i);
        if (i + 3 < NPG) loadK(kvA, i + 3);
        computeK(kvB, i + 1);
        if (i + 4 < NPG) loadK(kvB, i + 4);
        computeK(kvC, i + 2);
    }

    #pragma unroll
    for (int ci = 0; ci < 8; ++ci) {
        vfloat4 a; a.x = acc[ci][0]; a.y = acc[ci][1]; a.z = acc[ci][2]; a.w = acc[ci][3];
        *reinterpret_cast<vfloat4*>(
            accP + (((size_t)(b * 4 + g)) * CB + cg * 8 + ci) * VV + v0 + vq * 4) = a;
    }
    if (cg == 0) {
        vfloat4 lv; lv.x = l0; lv.y = l1; lv.z = l2; lv.w = l3;
        *reinterpret_cast<vfloat4*>(lP + ((size_t)(b * 4 + g)) * VV + v0 + vq * 4) = lv;
    }
}

// ================= K2a: combine partials + LayerNorm + il =================
__global__ __launch_bounds__(128, 4)
void combine_kernel(const float* __restrict__ accP, const float* __restrict__ lP,
                    const float* __restrict__ gam, const float* __restrict__ bet,
                    float* __restrict__ out, float* __restrict__ ws_il)
{
    const int gv = blockIdx.x * 128 + threadIdx.x;
    const int b  = gv / VV;
    const int v  = gv - b * VV;

    float lt = 0.f;
    #pragma unroll
    for (int g = 0; g < 4; ++g) lt += lP[((size_t)(b * 4 + g)) * VV + v];
    const float il = 1.f / lt;
    ws_il[(size_t)b * VV + v] = il;

    float f[CB], mu = 0.f;
    #pragma unroll
    for (int c = 0; c < CB; ++c) {
        float s = 0.f;
        #pragma unroll
        for (int g = 0; g < 4; ++g)
            s += accP[(((size_t)(b * 4 + g)) * CB + c) * VV + v];
        f[c] = s * il;
        mu += f[c];
    }
    mu *= (1.f / CB);
    float var = 0.f;
    #pragma unroll
    for (int c = 0; c < CB; ++c) { const float d = f[c] - mu; var = fmaf(d, d, var); }
    const float rs = rsqrtf(var * (1.f / CB) + 1e-5f);
    float* op = out + (size_t)b * CB * VV + v;
    #pragma unroll
    for (int c = 0; c < CB; ++c)
        op[(size_t)c * VV] = (f[c] - mu) * rs * gam[c] + bet[c];
}

// ============ K2b: normalize W (fp16) + transpose -> attn out =============
__global__ __launch_bounds__(256, 2)
void attnout_kernel(const unsigned short* __restrict__ wsW,
                    const float* __restrict__ ws_il, float* __restrict__ attn)
{
    __shared__ float W_s[NN * 68];   // [n][64v], pad 68: conflict-free both phases
    __shared__ float il_s[64];
    const int t  = threadIdx.x;
    const int b  = blockIdx.x / 216;
    const int v0 = (blockIdx.x % 216) * 64;

    if (t < 64) il_s[t] = ws_il[(size_t)b * VV + v0 + t];
    for (int k = t; k < NN * 16; k += 256) {      // 180 n x 16 quads
        const int n = k >> 4, part = k & 15;
        uint2 uu = *reinterpret_cast<const uint2*>(
            wsW + ((size_t)(b * NN + n)) * VV + v0 + part * 4);
        __half2 h01 = *reinterpret_cast<__half2*>(&uu.x);
        __half2 h23 = *reinterpret_cast<__half2*>(&uu.y);
        float2 f01 = __half22float2(h01);
        float2 f23 = __half22float2(h23);
        vfloat4 fv; fv.x = f01.x; fv.y = f01.y; fv.z = f23.x; fv.w = f23.y;
        *reinterpret_cast<vfloat4*>(&W_s[n * 68 + part * 4]) = fv;
    }
    __syncthreads();

    const int v = t >> 2, seg = t & 3;
    const float il = il_s[v];
    float* arow = attn + ((size_t)b * VV + v0 + v) * NN;
    #pragma unroll 1
    for (int q4 = seg; q4 < NN / 4; q4 += 4) {
        vfloat4 val;
        val.x = W_s[(q4 * 4 + 0) * 68 + v] * il;
        val.y = W_s[(q4 * 4 + 1) * 68 + v] * il;
        val.z = W_s[(q4 * 4 + 2) * 68 + v] * il;
        val.w = W_s[(q4 * 4 + 3) * 68 + v] * il;
        *reinterpret_cast<vfloat4*>(arow + q4 * 4) = val;   // row base 720B aligned
    }
}

// ===================== Fallback: R4 single kernel ==========================
__global__ __launch_bounds__(256, 2)
void vmat_attn_fallback(const float* __restrict__ ct, const float* __restrict__ beam,
                        const float* __restrict__ qw, const float* __restrict__ qb,
                        const float* __restrict__ gam, const float* __restrict__ bet,
                        float* __restrict__ out)
{
    __shared__ __align__(16) float Wbuf[NN * 64];
    __shared__ __align__(16) float Pbuf[4][CB][64];
    __shared__ __align__(16) float l_part[4][64];
    __shared__ float l_final[64];
    __shared__ float qb_s[CB], gam_s[CB], bet_s[CB];

    const int t = threadIdx.x, lane = t & 63, g = t >> 6;
    const int vq = lane & 15, cg = lane >> 4;
    const int bid = blockIdx.x, b = bid / 216, v0 = (bid % 216) * 64;

    for (int i = t; i < CB * C_CT; i += 256) Wbuf[i] = qw[i];
    if (t < CB) { qb_s[t] = qb[t]; gam_s[t] = gam[t]; bet_s[t] = bet[t]; }
    __syncthreads();
    {
        const int v = v0 + lane;
        const float* ctp = ct + ((size_t)b * C_CT + g * 32) * VV + v;
        float ctv[32];
        #pragma unroll
        for (int j = 0; j < 32; ++j) ctv[j] = ctp[(size_t)j * VV];
        float qp[CB];
        #pragma unroll
        for (int o = 0; o < CB; ++o) qp[o] = 0.f;
        for (int j = 0; j < 32; ++j) {
            #pragma unroll
            for (int o = 0; o < CB; ++o)
                qp[o] = fmaf(Wbuf[o * C_CT + g * 32 + j], ctv[j], qp[o]);
        }
        #pragma unroll
        for (int o = 0; o < CB; ++o) Pbuf[g][o][lane] = qp[o];
    }
    __syncthreads();
    float q[8][4];
    #pragma unroll
    for (int ci = 0; ci < 8; ++ci) {
        const int o = cg * 8 + ci;
        vfloat4 a0 = *reinterpret_cast<const vfloat4*>(&Pbuf[0][o][vq * 4]);
        vfloat4 a1 = *reinterpret_cast<const vfloat4*>(&Pbuf[1][o][vq * 4]);
        vfloat4 a2 = *reinterpret_cast<const vfloat4*>(&Pbuf[2][o][vq * 4]);
        vfloat4 a3 = *reinterpret_cast<const vfloat4*>(&Pbuf[3][o][vq * 4]);
        q[ci][0] = a0.x + a1.x + a2.x + a3.x + qb_s[o];
        q[ci][1] = a0.y + a1.y + a2.y + a3.y + qb_s[o];
        q[ci][2] = a0.z + a1.z + a2.z + a3.z + qb_s[o];
        q[ci][3] = a0.w + a1.w + a2.w + a3.w + qb_s[o];
    }
    __syncthreads();
    float acc[8][4];
    #pragma unroll
    for (int ci = 0; ci < 8; ++ci)
        acc[ci][0] = acc[ci][1] = acc[ci][2] = acc[ci][3] = 0.f;
    float l0 = 0.f, l1 = 0.f, l2 = 0.f, l3 = 0.f;
    const float* bp0 = beam + (((size_t)b * NN + g * NPG) * CB + cg * 8) * VV + v0 + vq * 4;
    vfloat4 kvA[8], kvB[8];
    auto loadK = [&](vfloat4* kv, int i) {
        const float* bp = bp0 + (size_t)i * CB * VV;
        #pragma unroll
        for (int ci = 0; ci < 8; ++ci)
            kv[ci] = __builtin_nontemporal_load(
                reinterpret_cast<const vfloat4*>(bp + (size_t)ci * VV));
    };
    auto computeK = [&](const vfloat4* kv, int i) {
        float p0 = 0.f, p1 = 0.f, p2 = 0.f, p3 = 0.f;
        #pragma unroll
        for (int ci = 0; ci < 8; ++ci) {
            p0 = fmaf(q[ci][0], kv[ci].x, p0);
            p1 = fmaf(q[ci][1], kv[ci].y, p1);
            p2 = fmaf(q[ci][2], kv[ci].z, p2);
            p3 = fmaf(q[ci][3], kv[ci].w, p3);
        }
        p0 += __shfl_xor(p0, 16); p1 += __shfl_xor(p1, 16);
        p2 += __shfl_xor(p2, 16); p3 += __shfl_xor(p3, 16);
        p0 += __shfl_xor(p0, 32); p1 += __shfl_xor(p1, 32);
        p2 += __shfl_xor(p2, 32); p3 += __shfl_xor(p3, 32);
        float w0 = __expf(fminf(p0 * SCALE, 60.f));
        float w1 = __expf(fminf(p1 * SCALE, 60.f));
        float w2 = __expf(fminf(p2 * SCALE, 60.f));
        float w3 = __expf(fminf(p3 * SCALE, 60.f));
        if (cg == 0) {
            vfloat4 wv; wv.x = w0; wv.y = w1; wv.z = w2; wv.w = w3;
            *reinterpret_cast<vfloat4*>(&Wbuf[(g * NPG + i) * 64 + vq * 4]) = wv;
        }
        l0 += w0; l1 += w1; l2 += w2; l3 += w3;
        #pragma unroll
        for (int ci = 0; ci < 8; ++ci) {
            acc[ci][0] = fmaf(w0, kv[ci].x, acc[ci][0]);
            acc[ci][1] = fmaf(w1, kv[ci].y, acc[ci][1]);
            acc[ci][2] = fmaf(w2, kv[ci].z, acc[ci][2]);
            acc[ci][3] = fmaf(w3, kv[ci].w, acc[ci][3]);
        }
    };
    loadK(kvA, 0);
    #pragma unroll 1
    for (int i = 0; i < NPG - 1; i += 2) {
        loadK(kvB, i + 1);
        computeK(kvA, i);
        if (i + 2 < NPG) loadK(kvA, i + 2);
        computeK(kvB, i + 1);
    }
    computeK(kvA, NPG - 1);
    #pragma unroll
    for (int ci = 0; ci < 8; ++ci) {
        vfloat4 a; a.x = acc[ci][0]; a.y = acc[ci][1]; a.z = acc[ci][2]; a.w = acc[ci][3];
        *reinterpret_cast<vfloat4*>(&Pbuf[g][cg * 8 + ci][vq * 4]) = a;
    }
    if (cg == 0) {
        vfloat4 lv; lv.x = l0; lv.y = l1; lv.z = l2; lv.w = l3;
        *reinterpret_cast<vfloat4*>(&l_part[g][vq * 4]) = lv;
    }
    __syncthreads();
    if (t < 64) {
        float lt = l_part[0][t] + l_part[1][t] + l_part[2][t] + l_part[3][t];
        l_final[t] = lt;
        float inv_l = 1.f / lt;
        float f[CB], mu = 0.f;
        #pragma unroll
        for (int c = 0; c < CB; ++c) {
            f[c] = (Pbuf[0][c][t] + Pbuf[1][c][t] + Pbuf[2][c][t] + Pbuf[3][c][t]) * inv_l;
            mu += f[c];
        }
        mu *= (1.f / CB);
        float var = 0.f;
        #pragma unroll
        for (int c = 0; c < CB; ++c) { float d = f[c] - mu; var = fmaf(d, d, var); }
        float rs = rsqrtf(var * (1.f / CB) + 1e-5f);
        float* op = out + (size_t)b * CB * VV + v0 + t;
        #pragma unroll
        for (int c = 0; c < CB; ++c)
            op[(size_t)c * VV] = (f[c] - mu) * rs * gam_s[c] + bet_s[c];
    }
    __syncthreads();
    {
        const int vv = t & 63, j = t >> 6;
        const float inv_l = 1.f / l_final[vv];
        float* arow = out + (size_t)BB * CB * VV + ((size_t)b * VV + v0 + vv) * NN;
        const int q4b = j * 12, q4e = (j == 3) ? 45 : (j * 12 + 12);
        for (int q4 = q4b; q4 < q4e; ++q4) {
            const int n0 = q4 * 4;
            vfloat4 val;
            val.x = Wbuf[(n0 + 0) * 64 + vv] * inv_l;
            val.y = Wbuf[(n0 + 1) * 64 + vv] * inv_l;
            val.z = Wbuf[(n0 + 2) * 64 + vv] * inv_l;
            val.w = Wbuf[(n0 + 3) * 64 + vv] * inv_l;
            *reinterpret_cast<vfloat4*>(arow + n0) = val;
        }
    }
}

// ================================ launch ==================================
extern "C" void kernel_launch(void* const* d_in, const int* in_sizes, int n_in,
                              void* d_out, int out_size, void* d_ws, size_t ws_size,
                              hipStream_t stream) {
    (void)in_sizes; (void)n_in; (void)out_size;
    const float* ct   = (const float*)d_in[0];
    const float* beam = (const float*)d_in[1];
    const float* qw   = (const float*)d_in[2];
    const float* qb   = (const float*)d_in[3];
    const float* gam  = (const float*)d_in[4];
    const float* bet  = (const float*)d_in[5];
    float* out = (float*)d_out;

    const size_t W_HALFS   = (size_t)BB * NN * VV;            // 4,976,640 halfs = 9.95 MB
    const size_t WS_NEEDED = W_HALFS * 2 + (size_t)BB * VV * 4;  // + il -> 10.06 MB

    if (ws_size >= WS_NEEDED) {
        unsigned short* wsW = (unsigned short*)d_ws;
        float* ws_il = (float*)((char*)d_ws + W_HALFS * 2);
        float* qarr  = out;                                   // fused region (dead until K2a)
        float* attn  = out + (size_t)BB * CB * VV;            // attn region
        float* accP  = attn;                                  // scratch until K2b
        float* lP    = attn + (size_t)BB * 4 * CB * VV;       // 14.16..14.6 MB of 19.9
        qproj_kernel  <<<dim3(BB * 216), 256, 0, stream>>>(ct, qw, qb, qarr);
        stream_kernel <<<dim3(BB * 864),  64, 0, stream>>>(beam, qarr, wsW, accP, lP);
        combine_kernel<<<dim3(BB * VV / 128), 128, 0, stream>>>(accP, lP, gam, bet, out, ws_il);
        attnout_kernel<<<dim3(BB * 216), 256, 0, stream>>>(wsW, ws_il, attn);
    } else {
        vmat_attn_fallback<<<dim3(BB * 216), 256, 0, stream>>>(ct, beam, qw, qb, gam, bet, out);
    }
}

// Round 9
// 155.478 us; speedup vs baseline: 1.2313x; 1.1791x over previous
//
#include <hip/hip_runtime.h>
#include <math.h>

#define BB      2
#define C_CT    128
#define CB      32
#define NN      180
#define VV      13824      // 24*24*24
#define VOXB    64         // voxels per block
#define GR      4          // n-groups (one per wave)
#define NPG     45         // NN / GR
#define THREADS 256

typedef float vfloat4 __attribute__((ext_vector_type(4)));

__global__ __launch_bounds__(THREADS, 2)
void vmat_attn_kernel(const float* __restrict__ ct, const float* __restrict__ beam,
                      const float* __restrict__ qw, const float* __restrict__ qb,
                      const float* __restrict__ gam, const float* __restrict__ bet,
                      float* __restrict__ out)
{
    // Wbuf: phase1 = q_w staging [32][128]; phase4+ = unnorm weights W[n=180][vox=64] (46KB)
    __shared__ __align__(16) float Wbuf[NN * VOXB];
    // Pbuf: phase2 = q partials [g][o][vox]; phase5 = acc partials [g][c][vox] (32KB)
    __shared__ __align__(16) float Pbuf[GR][CB][VOXB];
    __shared__ __align__(16) float l_part[GR][VOXB];
    __shared__ float l_final[VOXB];
    __shared__ float qb_s[CB], gam_s[CB], bet_s[CB];

    const int t    = threadIdx.x;
    const int lane = t & 63;
    const int g    = t >> 6;      // wave id = n-group
    const int vq   = lane & 15;   // voxel quad (voxels vq*4..vq*4+3)
    const int cg   = lane >> 4;   // channel group (channels cg*8..cg*8+7)
    const int bid  = blockIdx.x;
    const int b    = bid / (VV / VOXB);
    const int v0   = (bid % (VV / VOXB)) * VOXB;

    // ---- beam addressing + EARLY issue of first two kv batches ----
    // (independent of q; hides phase-1/2 latency under HBM)
    const float* bp0 = beam + (((size_t)b * NN + g * NPG) * CB + cg * 8) * VV + v0 + vq * 4;
    vfloat4 kvA[8], kvB[8], kvC[8];
    auto loadK = [&](vfloat4* kv, int i) {
        const float* bp = bp0 + (size_t)i * CB * VV;
        #pragma unroll
        for (int ci = 0; ci < 8; ++ci)
            kv[ci] = __builtin_nontemporal_load(
                reinterpret_cast<const vfloat4*>(bp + (size_t)ci * VV));
    };
    loadK(kvA, 0);
    loadK(kvB, 1);

    // ---- phase 1: stage q_w + small params ----
    for (int i = t; i < CB * C_CT; i += THREADS) Wbuf[i] = qw[i];
    if (t < CB) { qb_s[t] = qb[t]; gam_s[t] = gam[t]; bet_s[t] = bet[t]; }
    __syncthreads();

    // ---- phase 2: q projection partials; wave g covers cc in [32g, 32g+32) ----
    {
        const int v = v0 + lane;
        const float* ctp = ct + ((size_t)b * C_CT + g * 32) * VV + v;
        float ctv[32];
        #pragma unroll
        for (int j = 0; j < 32; ++j) ctv[j] = ctp[(size_t)j * VV];
        float qp[CB];
        #pragma unroll
        for (int o = 0; o < CB; ++o) qp[o] = 0.f;
        for (int j = 0; j < 32; ++j) {
            #pragma unroll
            for (int o = 0; o < CB; ++o)
                qp[o] = fmaf(Wbuf[o * C_CT + g * 32 + j], ctv[j], qp[o]);
        }
        #pragma unroll
        for (int o = 0; o < CB; ++o) Pbuf[g][o][lane] = qp[o];
    }
    __syncthreads();

    // ---- phase 3: each lane gathers q[8 ch][4 vox] from partials ----
    float q[8][4];
    #pragma unroll
    for (int ci = 0; ci < 8; ++ci) {
        const int o = cg * 8 + ci;
        float4 a0 = *reinterpret_cast<const float4*>(&Pbuf[0][o][vq * 4]);
        float4 a1 = *reinterpret_cast<const float4*>(&Pbuf[1][o][vq * 4]);
        float4 a2 = *reinterpret_cast<const float4*>(&Pbuf[2][o][vq * 4]);
        float4 a3 = *reinterpret_cast<const float4*>(&Pbuf[3][o][vq * 4]);
        q[ci][0] = a0.x + a1.x + a2.x + a3.x + qb_s[o];
        q[ci][1] = a0.y + a1.y + a2.y + a3.y + qb_s[o];
        q[ci][2] = a0.z + a1.z + a2.z + a3.z + qb_s[o];
        q[ci][3] = a0.w + a1.w + a2.w + a3.w + qb_s[o];
    }
    __syncthreads();   // Pbuf/Wbuf reuse below

    // ---- phase 4: fused logits + exp + weighted accum; 3-deep prefetch ----
    const float scale = 0.17677669529663687f;  // 32^-0.5
    float acc[8][4];
    #pragma unroll
    for (int ci = 0; ci < 8; ++ci)
        acc[ci][0] = acc[ci][1] = acc[ci][2] = acc[ci][3] = 0.f;
    float l0 = 0.f, l1 = 0.f, l2 = 0.f, l3 = 0.f;

    auto computeK = [&](const vfloat4* kv, int i) {
        float p0 = 0.f, p1 = 0.f, p2 = 0.f, p3 = 0.f;
        #pragma unroll
        for (int ci = 0; ci < 8; ++ci) {
            p0 = fmaf(q[ci][0], kv[ci].x, p0);
            p1 = fmaf(q[ci][1], kv[ci].y, p1);
            p2 = fmaf(q[ci][2], kv[ci].z, p2);
            p3 = fmaf(q[ci][3], kv[ci].w, p3);
        }
        p0 += __shfl_xor(p0, 16); p1 += __shfl_xor(p1, 16);
        p2 += __shfl_xor(p2, 16); p3 += __shfl_xor(p3, 16);
        p0 += __shfl_xor(p0, 32); p1 += __shfl_xor(p1, 32);
        p2 += __shfl_xor(p2, 32); p3 += __shfl_xor(p3, 32);
        float w0 = __expf(fminf(p0 * scale, 60.f));
        float w1 = __expf(fminf(p1 * scale, 60.f));
        float w2 = __expf(fminf(p2 * scale, 60.f));
        float w3 = __expf(fminf(p3 * scale, 60.f));
        if (cg == 0) {
            float4 wv; wv.x = w0; wv.y = w1; wv.z = w2; wv.w = w3;
            *reinterpret_cast<float4*>(&Wbuf[(g * NPG + i) * VOXB + vq * 4]) = wv;
        }
        l0 += w0; l1 += w1; l2 += w2; l3 += w3;
        #pragma unroll
        for (int ci = 0; ci < 8; ++ci) {
            acc[ci][0] = fmaf(w0, kv[ci].x, acc[ci][0]);
            acc[ci][1] = fmaf(w1, kv[ci].y, acc[ci][1]);
            acc[ci][2] = fmaf(w2, kv[ci].z, acc[ci][2]);
            acc[ci][3] = fmaf(w3, kv[ci].w, acc[ci][3]);
        }
    };

    #pragma unroll 1
    for (int i = 0; i < NPG; i += 3) {        // 45 = 3*15, exact
        loadK(kvC, i + 2);                    // keep ~24 loads in flight
        computeK(kvA, i);
        if (i + 3 < NPG) loadK(kvA, i + 3);
        computeK(kvB, i + 1);
        if (i + 4 < NPG) loadK(kvB, i + 4);
        computeK(kvC, i + 2);
    }

    // ---- phase 5: spill partials ----
    #pragma unroll
    for (int ci = 0; ci < 8; ++ci) {
        float4 av; av.x = acc[ci][0]; av.y = acc[ci][1]; av.z = acc[ci][2]; av.w = acc[ci][3];
        *reinterpret_cast<float4*>(&Pbuf[g][cg * 8 + ci][vq * 4]) = av;
    }
    if (cg == 0) {
        float4 lv; lv.x = l0; lv.y = l1; lv.z = l2; lv.w = l3;
        *reinterpret_cast<float4*>(&l_part[g][vq * 4]) = lv;
    }
    __syncthreads();

    // ---- phase 6: combine + LayerNorm + fused output (wave 0) ----
    if (t < VOXB) {
        float lt = l_part[0][t] + l_part[1][t] + l_part[2][t] + l_part[3][t];
        l_final[t] = lt;
        float inv_l = 1.f / lt;
        float f[CB], mu = 0.f;
        #pragma unroll
        for (int c = 0; c < CB; ++c) {
            f[c] = (Pbuf[0][c][t] + Pbuf[1][c][t] + Pbuf[2][c][t] + Pbuf[3][c][t]) * inv_l;
            mu += f[c];
        }
        mu *= (1.f / CB);
        float var = 0.f;
        #pragma unroll
        for (int c = 0; c < CB; ++c) { float d = f[c] - mu; var = fmaf(d, d, var); }
        float rs = rsqrtf(var * (1.f / CB) + 1e-5f);
        float* op = out + (size_t)b * CB * VV + v0 + t;
        #pragma unroll
        for (int c = 0; c < CB; ++c)
            op[(size_t)c * VV] = (f[c] - mu) * rs * gam_s[c] + bet_s[c];
    }
    __syncthreads();

    // ---- phase 7: normalized attn weights, aligned float4 stores ----
    {
        const int vv = t & 63;
        const int j  = t >> 6;
        const float inv_l = 1.f / l_final[vv];
        float* arow = out + (size_t)BB * CB * VV + ((size_t)b * VV + v0 + vv) * NN;
        const int q4_begin = j * 12;
        const int q4_end   = (j == 3) ? 45 : (j * 12 + 12);   // 45 float4 = 180 floats
        for (int q4 = q4_begin; q4 < q4_end; ++q4) {
            const int n0 = q4 * 4;
            float4 val;
            val.x = Wbuf[(n0 + 0) * VOXB + vv] * inv_l;
            val.y = Wbuf[(n0 + 1) * VOXB + vv] * inv_l;
            val.z = Wbuf[(n0 + 2) * VOXB + vv] * inv_l;
            val.w = Wbuf[(n0 + 3) * VOXB + vv] * inv_l;
            *reinterpret_cast<float4*>(arow + n0) = val;   // row base 720B = 16-aligned
        }
    }
}

extern "C" void kernel_launch(void* const* d_in, const int* in_sizes, int n_in,
                              void* d_out, int out_size, void* d_ws, size_t ws_size,
                              hipStream_t stream) {
    (void)in_sizes; (void)n_in; (void)out_size; (void)d_ws; (void)ws_size;
    const float* ct   = (const float*)d_in[0];
    const float* beam = (const float*)d_in[1];
    const float* qw   = (const float*)d_in[2];
    const float* qb   = (const float*)d_in[3];
    const float* gam  = (const float*)d_in[4];
    const float* bet  = (const float*)d_in[5];
    float* out = (float*)d_out;
    dim3 grid(BB * (VV / VOXB));   // 432 blocks
    vmat_attn_kernel<<<grid, THREADS, 0, stream>>>(ct, beam, qw, qb, gam, bet, out);
}

// Round 10
// 142.573 us; speedup vs baseline: 1.3427x; 1.0905x over previous
//
#include <hip/hip_runtime.h>
#include <math.h>

#define BB      2
#define C_CT    128
#define CB      32
#define NN      180
#define VV      13824      // 24*24*24
#define VOXB    64         // voxels per block
#define GR      4          // n-groups (one per wave)
#define NPG     45         // NN / GR
#define THREADS 256

typedef float vfloat4 __attribute__((ext_vector_type(4)));

// Champion (R4 structure, 142.5 us measured):
//  - single kernel, 432 blocks x 256 threads, 2 blocks/CU (80KB LDS)
//  - beam read exactly once; 256B contiguous segments per (channel,n) per wave
//  - 2-deep ping-pong prefetch with nontemporal float4 loads
//  - per-CU rate 21.2 GB/s = 86% of m13 per-CU copy rate; 432-block
//    quantization (1.185x) is arithmetically irreducible at >=32-voxel
//    aligned tiles. Measured alternatives all regress (R3/R5/R6/R7/R8/R9).
__global__ __launch_bounds__(THREADS, 2)
void vmat_attn_kernel(const float* __restrict__ ct, const float* __restrict__ beam,
                      const float* __restrict__ qw, const float* __restrict__ qb,
                      const float* __restrict__ gam, const float* __restrict__ bet,
                      float* __restrict__ out)
{
    // Wbuf: phase1 = q_w staging [32][128]; phase4+ = unnorm weights W[n=180][vox=64] (46KB)
    __shared__ __align__(16) float Wbuf[NN * VOXB];
    // Pbuf: phase2 = q partials [g][o][vox]; phase5 = acc partials [g][c][vox] (32KB)
    __shared__ __align__(16) float Pbuf[GR][CB][VOXB];
    __shared__ __align__(16) float l_part[GR][VOXB];
    __shared__ float l_final[VOXB];
    __shared__ float qb_s[CB], gam_s[CB], bet_s[CB];

    const int t    = threadIdx.x;
    const int lane = t & 63;
    const int g    = t >> 6;      // wave id = n-group
    const int vq   = lane & 15;   // voxel quad (voxels vq*4..vq*4+3)
    const int cg   = lane >> 4;   // channel group (channels cg*8..cg*8+7)
    const int bid  = blockIdx.x;
    const int b    = bid / (VV / VOXB);
    const int v0   = (bid % (VV / VOXB)) * VOXB;

    // ---- phase 1: stage q_w + small params ----
    for (int i = t; i < CB * C_CT; i += THREADS) Wbuf[i] = qw[i];
    if (t < CB) { qb_s[t] = qb[t]; gam_s[t] = gam[t]; bet_s[t] = bet[t]; }
    __syncthreads();

    // ---- phase 2: q projection partials; wave g covers cc in [32g, 32g+32) ----
    {
        const int v = v0 + lane;
        const float* ctp = ct + ((size_t)b * C_CT + g * 32) * VV + v;
        float ctv[32];
        #pragma unroll
        for (int j = 0; j < 32; ++j) ctv[j] = ctp[(size_t)j * VV];
        float qp[CB];
        #pragma unroll
        for (int o = 0; o < CB; ++o) qp[o] = 0.f;
        for (int j = 0; j < 32; ++j) {
            #pragma unroll
            for (int o = 0; o < CB; ++o)
                qp[o] = fmaf(Wbuf[o * C_CT + g * 32 + j], ctv[j], qp[o]);
        }
        #pragma unroll
        for (int o = 0; o < CB; ++o) Pbuf[g][o][lane] = qp[o];
    }
    __syncthreads();

    // ---- phase 3: each lane gathers q[8 ch][4 vox] from partials ----
    float q[8][4];
    #pragma unroll
    for (int ci = 0; ci < 8; ++ci) {
        const int o = cg * 8 + ci;
        float4 a0 = *reinterpret_cast<const float4*>(&Pbuf[0][o][vq * 4]);
        float4 a1 = *reinterpret_cast<const float4*>(&Pbuf[1][o][vq * 4]);
        float4 a2 = *reinterpret_cast<const float4*>(&Pbuf[2][o][vq * 4]);
        float4 a3 = *reinterpret_cast<const float4*>(&Pbuf[3][o][vq * 4]);
        q[ci][0] = a0.x + a1.x + a2.x + a3.x + qb_s[o];
        q[ci][1] = a0.y + a1.y + a2.y + a3.y + qb_s[o];
        q[ci][2] = a0.z + a1.z + a2.z + a3.z + qb_s[o];
        q[ci][3] = a0.w + a1.w + a2.w + a3.w + qb_s[o];
    }
    __syncthreads();   // Pbuf/Wbuf reuse below

    // ---- phase 4: fused logits + exp + weighted accum; 2-deep ping-pong prefetch ----
    const float scale = 0.17677669529663687f;  // 32^-0.5
    float acc[8][4];
    #pragma unroll
    for (int ci = 0; ci < 8; ++ci)
        acc[ci][0] = acc[ci][1] = acc[ci][2] = acc[ci][3] = 0.f;
    float l0 = 0.f, l1 = 0.f, l2 = 0.f, l3 = 0.f;
    const float* bp0 = beam + (((size_t)b * NN + g * NPG) * CB + cg * 8) * VV + v0 + vq * 4;

    vfloat4 kvA[8], kvB[8];
    auto loadK = [&](vfloat4* kv, int i) {
        const float* bp = bp0 + (size_t)i * CB * VV;
        #pragma unroll
        for (int ci = 0; ci < 8; ++ci)
            kv[ci] = __builtin_nontemporal_load(
                reinterpret_cast<const vfloat4*>(bp + (size_t)ci * VV));
    };
    auto computeK = [&](const vfloat4* kv, int i) {
        float p0 = 0.f, p1 = 0.f, p2 = 0.f, p3 = 0.f;
        #pragma unroll
        for (int ci = 0; ci < 8; ++ci) {
            p0 = fmaf(q[ci][0], kv[ci].x, p0);
            p1 = fmaf(q[ci][1], kv[ci].y, p1);
            p2 = fmaf(q[ci][2], kv[ci].z, p2);
            p3 = fmaf(q[ci][3], kv[ci].w, p3);
        }
        p0 += __shfl_xor(p0, 16); p1 += __shfl_xor(p1, 16);
        p2 += __shfl_xor(p2, 16); p3 += __shfl_xor(p3, 16);
        p0 += __shfl_xor(p0, 32); p1 += __shfl_xor(p1, 32);
        p2 += __shfl_xor(p2, 32); p3 += __shfl_xor(p3, 32);
        float w0 = __expf(fminf(p0 * scale, 60.f));
        float w1 = __expf(fminf(p1 * scale, 60.f));
        float w2 = __expf(fminf(p2 * scale, 60.f));
        float w3 = __expf(fminf(p3 * scale, 60.f));
        if (cg == 0) {
            float4 wv; wv.x = w0; wv.y = w1; wv.z = w2; wv.w = w3;
            *reinterpret_cast<float4*>(&Wbuf[(g * NPG + i) * VOXB + vq * 4]) = wv;
        }
        l0 += w0; l1 += w1; l2 += w2; l3 += w3;
        #pragma unroll
        for (int ci = 0; ci < 8; ++ci) {
            acc[ci][0] = fmaf(w0, kv[ci].x, acc[ci][0]);
            acc[ci][1] = fmaf(w1, kv[ci].y, acc[ci][1]);
            acc[ci][2] = fmaf(w2, kv[ci].z, acc[ci][2]);
            acc[ci][3] = fmaf(w3, kv[ci].w, acc[ci][3]);
        }
    };

    loadK(kvA, 0);
    #pragma unroll 1
    for (int i = 0; i < NPG - 1; i += 2) {
        loadK(kvB, i + 1);          // issue next loads BEFORE consuming kvA
        computeK(kvA, i);
        if (i + 2 < NPG) loadK(kvA, i + 2);
        computeK(kvB, i + 1);
    }
    computeK(kvA, NPG - 1);   // n=44, loaded in last loop iteration

    // ---- phase 5: spill partials ----
    #pragma unroll
    for (int ci = 0; ci < 8; ++ci) {
        float4 av; av.x = acc[ci][0]; av.y = acc[ci][1]; av.z = acc[ci][2]; av.w = acc[ci][3];
        *reinterpret_cast<float4*>(&Pbuf[g][cg * 8 + ci][vq * 4]) = av;
    }
    if (cg == 0) {
        float4 lv; lv.x = l0; lv.y = l1; lv.z = l2; lv.w = l3;
        *reinterpret_cast<float4*>(&l_part[g][vq * 4]) = lv;
    }
    __syncthreads();

    // ---- phase 6: combine + LayerNorm + fused output (wave 0) ----
    if (t < VOXB) {
        float lt = l_part[0][t] + l_part[1][t] + l_part[2][t] + l_part[3][t];
        l_final[t] = lt;
        float inv_l = 1.f / lt;
        float f[CB], mu = 0.f;
        #pragma unroll
        for (int c = 0; c < CB; ++c) {
            f[c] = (Pbuf[0][c][t] + Pbuf[1][c][t] + Pbuf[2][c][t] + Pbuf[3][c][t]) * inv_l;
            mu += f[c];
        }
        mu *= (1.f / CB);
        float var = 0.f;
        #pragma unroll
        for (int c = 0; c < CB; ++c) { float d = f[c] - mu; var = fmaf(d, d, var); }
        float rs = rsqrtf(var * (1.f / CB) + 1e-5f);
        float* op = out + (size_t)b * CB * VV + v0 + t;
        #pragma unroll
        for (int c = 0; c < CB; ++c)
            op[(size_t)c * VV] = (f[c] - mu) * rs * gam_s[c] + bet_s[c];
    }
    __syncthreads();

    // ---- phase 7: normalized attn weights, aligned float4 stores ----
    {
        const int vv = t & 63;
        const int j  = t >> 6;
        const float inv_l = 1.f / l_final[vv];
        float* arow = out + (size_t)BB * CB * VV + ((size_t)b * VV + v0 + vv) * NN;
        const int q4_begin = j * 12;
        const int q4_end   = (j == 3) ? 45 : (j * 12 + 12);   // 45 float4 = 180 floats
        for (int q4 = q4_begin; q4 < q4_end; ++q4) {
            const int n0 = q4 * 4;
            float4 val;
            val.x = Wbuf[(n0 + 0) * VOXB + vv] * inv_l;
            val.y = Wbuf[(n0 + 1) * VOXB + vv] * inv_l;
            val.z = Wbuf[(n0 + 2) * VOXB + vv] * inv_l;
            val.w = Wbuf[(n0 + 3) * VOXB + vv] * inv_l;
            *reinterpret_cast<float4*>(arow + n0) = val;   // row base 720B = 16-aligned
        }
    }
}

extern "C" void kernel_launch(void* const* d_in, const int* in_sizes, int n_in,
                              void* d_out, int out_size, void* d_ws, size_t ws_size,
                              hipStream_t stream) {
    (void)in_sizes; (void)n_in; (void)out_size; (void)d_ws; (void)ws_size;
    const float* ct   = (const float*)d_in[0];
    const float* beam = (const float*)d_in[1];
    const float* qw   = (const float*)d_in[2];
    const float* qb   = (const float*)d_in[3];
    const float* gam  = (const float*)d_in[4];
    const float* bet  = (const float*)d_in[5];
    float* out = (float*)d_out;
    dim3 grid(BB * (VV / VOXB));   // 432 blocks
    vmat_attn_kernel<<<grid, THREADS, 0, stream>>>(ct, beam, qw, qb, gam, bet, out);
}